// Round 2
// baseline (521.009 us; speedup 1.0000x reference)
//
#include <hip/hip_runtime.h>

#define M_DIM 8192
#define K_DIM 2048
#define N_DIM 5632

typedef __attribute__((ext_vector_type(8))) short short8;
typedef __attribute__((ext_vector_type(4))) float f32x4;

// fp32 -> bf16 round-to-nearest-even (bit trick; inputs are finite)
__device__ __forceinline__ short f2b(float f) {
  union { float f; unsigned u; } v; v.f = f;
  unsigned r = v.u + 0x7FFFu + ((v.u >> 16) & 1u);
  return (short)(r >> 16);
}

// async global->LDS, 16B per lane. LDS dest must be wave-uniform base + lane*16.
__device__ __forceinline__ void async16(void* lds, const void* g) {
  __builtin_amdgcn_global_load_lds(
      (const __attribute__((address_space(1))) unsigned*)g,
      (__attribute__((address_space(3))) unsigned*)lds,
      16, 0, 0);
}

// ---------------- Kernel 1: x fp32 -> bf16 -----------------------------------
__global__ __launch_bounds__(256) void cvt_x_kernel(const float* __restrict__ x,
                                                    short* __restrict__ xb) {
  long t = (long)blockIdx.x * 256 + threadIdx.x;   // 8 elements per thread
  const float4* xv = (const float4*)x;
  float4 f0 = xv[2 * t];
  float4 f1 = xv[2 * t + 1];
  short8 o;
  o[0] = f2b(f0.x); o[1] = f2b(f0.y); o[2] = f2b(f0.z); o[3] = f2b(f0.w);
  o[4] = f2b(f1.x); o[5] = f2b(f1.y); o[6] = f2b(f1.z); o[7] = f2b(f1.w);
  *(short8*)(xb + 8 * t) = o;
}

// ---------------- Kernel 2: dequant int4 + fold rank-16 LoRA into W' ---------
// W'[o][i] = (q - zero[g]) * scale[g] + 2 * sum_r A[i][r] * B[r][o]
__global__ __launch_bounds__(256) void dequant_lora_kernel(
    const int* __restrict__ packed, const float* __restrict__ scales,
    const float* __restrict__ zeros, const float* __restrict__ lA,
    const float* __restrict__ lB, short* __restrict__ wb) {
  int o = blockIdx.x;
  int i0 = threadIdx.x * 8;                  // first of 8 W elements in row o
  long e0 = (long)o * K_DIM + i0;            // flat W index
  int4 p = ((const int4*)packed)[e0 >> 3];   // 4 packed bytes -> 8 codes
  int g = (int)(e0 >> 7);                    // group of 128 (8 | 128, same group)
  float s = scales[g], z = zeros[g];

  // B column for this o, pre-scaled by lora 2.0 (uniform per block)
  float bcol[16];
#pragma unroll
  for (int r = 0; r < 16; ++r) bcol[r] = lB[r * N_DIM + o] * 2.0f;

  short8 out8;
#pragma unroll
  for (int d = 0; d < 4; ++d) {
    int pv = (&p.x)[d];                      // two nibbles
    float w0 = ((float)(pv & 0xF) - z) * s;        // element e0+2d   (low)
    float w1 = ((float)((pv >> 4) & 0xF) - z) * s; // element e0+2d+1 (high)
    const float4* a0 = (const float4*)&lA[(i0 + 2 * d) * 16];
    const float4* a1 = (const float4*)&lA[(i0 + 2 * d + 1) * 16];
    float acc0 = 0.f, acc1 = 0.f;
#pragma unroll
    for (int r4 = 0; r4 < 4; ++r4) {
      float4 av0 = a0[r4], av1 = a1[r4];
      acc0 += av0.x * bcol[4 * r4] + av0.y * bcol[4 * r4 + 1] +
              av0.z * bcol[4 * r4 + 2] + av0.w * bcol[4 * r4 + 3];
      acc1 += av1.x * bcol[4 * r4] + av1.y * bcol[4 * r4 + 1] +
              av1.z * bcol[4 * r4 + 2] + av1.w * bcol[4 * r4 + 3];
    }
    out8[2 * d] = f2b(w0 + acc0);
    out8[2 * d + 1] = f2b(w1 + acc1);
  }
  *(short8*)(wb + e0) = out8;
}

// ---------------- Kernel 3: C[m][n] = sum_k X[m][k] * W'[n][k] ---------------
// 256x256 tile, BK=32, 8 waves (2Mx4N), per-wave 128x64 = acc[8][4].
// LDS: 4-deep K-tile ring (A:4x16KB, B:4x16KB = 128KB). Prefetch distance 3.
// ONE barrier per K-tile (end-of-tile, after counted vmcnt(8)).
// Hazard audit:
//   stage-vs-read: stage of tile k+3 (issued in tile k) targets buf (k-1)&3;
//     every wave's reads of that buf completed (data in regs, lgkmcnt'ed)
//     before it passed the end-of-tile-(k-1) barrier.
//   read-vs-stage-completion: per-wave vmcnt(8) at end of tile k leaves only
//     tiles k+2,k+3 (8 loads) in flight -> tile k+1 resident; barrier
//     publishes all waves' LDS writes.
// Intra-tile: no barriers -> waves desync; compiler emits counted lgkmcnt
// between ds_read and MFMA; af2 reads issued mid-cluster hide under MFMA.
// Swizzle: LDS slot s of row r holds global 16B-chunk s ^ ((r>>1)&3)
//   -> ds_read_b128 banks 2-way alias only (free, m136). Conflicts measured 0.
__global__ __launch_bounds__(512, 2) void gemm_kernel(const short* __restrict__ xb,
                                                      const short* __restrict__ wb,
                                                      float* __restrict__ out) {
  // [0,32768): A bufs (4 x 8192 shorts), [32768,65536): B bufs
  __shared__ __align__(16) short lds[65536];   // 128 KB

  const int tid = threadIdx.x;
  const int lane = tid & 63;
  const int wave = tid >> 6;
  const int wm = wave >> 2, wn = wave & 3;     // 2(M) x 4(N) wave grid
  const int l15 = lane & 15, quad = lane >> 4;

  // XCD-aware bijective swizzle: 704 blocks = 8 XCDs x 88
  int flat = blockIdx.x;
  int swz = (flat & 7) * 88 + (flat >> 3);
  int bm = swz / 22, bn = swz - bm * 22;
  const int m0 = bm * 256, n0 = bn * 256;

  const short* a_base = xb + (size_t)m0 * K_DIM;
  const short* b_base = wb + (size_t)n0 * K_DIM;

  // LDS read offsets (shorts). Row base is a multiple of 16, so
  // (row>>1)&3 == (l15>>1)&3 for every fragment row.
  const int rswz = quad ^ ((l15 >> 1) & 3);
  const int a_rd = (wm * 128 + l15) * 32 + rswz * 8;           // + mi*512 + buf
  const int b_rd = 32768 + (wn * 64 + l15) * 32 + rswz * 8;    // + ni*512 + buf

  // Staging: 4 x global_load_lds(16B)/thread/tile. row = tid>>2, slot = tid&3;
  // source chunk = slot ^ ((row>>1)&3) (inverse swz). Row srow+128 has the
  // same schunk since 128>>1 = 64 == 0 (mod 4).
  const int srow = tid >> 2;
  const int schunk = (tid & 3) ^ ((srow >> 1) & 3);
  const short* ag0 = a_base + (size_t)srow * K_DIM + schunk * 8;
  const short* ag1 = ag0 + (size_t)128 * K_DIM;
  const short* bg0 = b_base + (size_t)srow * K_DIM + schunk * 8;
  const short* bg1 = bg0 + (size_t)128 * K_DIM;
  const int sl0 = tid * 8, sl1 = (512 + tid) * 8;    // linear LDS dest (shorts)

  f32x4 acc[8][4] = {};

  // Prologue: stage K-tiles 0,1,2 into bufs 0,1,2 (12 loads); wait tile 0 only.
#pragma unroll
  for (int t = 0; t < 3; ++t) {
    const int sb = t * 8192;
    async16(&lds[sb + sl0], ag0 + t * 32);
    async16(&lds[sb + sl1], ag1 + t * 32);
    async16(&lds[32768 + sb + sl0], bg0 + t * 32);
    async16(&lds[32768 + sb + sl1], bg1 + t * 32);
  }
  asm volatile("s_waitcnt vmcnt(8)" ::: "memory");
  __builtin_amdgcn_s_barrier();

  // One K-tile, barrier-free interior:
  //   12 ds_read_b128 (bf, af1 up front; af2 mid-cluster), 4 stage issues,
  //   32 MFMA. Compiler inserts counted lgkmcnt before each first use.
  auto tile = [&](int k, bool do_stage) {
    const int bo = (k & 3) * 8192;         // compute buffer
    const int so = ((k + 3) & 3) * 8192;   // stage target (freed after tile k-1)
    short8 bf[4], af1[4], af2[4];
#pragma unroll
    for (int ni = 0; ni < 4; ++ni)
      bf[ni] = *(const short8*)&lds[bo + b_rd + ni * 512];
#pragma unroll
    for (int mi = 0; mi < 4; ++mi)
      af1[mi] = *(const short8*)&lds[bo + a_rd + mi * 512];
    if (do_stage) {
      async16(&lds[so + sl0], ag0 + (k + 3) * 32);
      async16(&lds[so + sl1], ag1 + (k + 3) * 32);
      async16(&lds[32768 + so + sl0], bg0 + (k + 3) * 32);
      async16(&lds[32768 + so + sl1], bg1 + (k + 3) * 32);
    }
    __builtin_amdgcn_s_setprio(1);
#pragma unroll
    for (int mi = 0; mi < 2; ++mi)
#pragma unroll
      for (int ni = 0; ni < 4; ++ni)
        acc[mi][ni] = __builtin_amdgcn_mfma_f32_16x16x32_bf16(
            af1[mi], bf[ni], acc[mi][ni], 0, 0, 0);
    __builtin_amdgcn_s_setprio(0);
    // issue af2 reads here: latency hides under the remaining MFMA work
#pragma unroll
    for (int mi = 0; mi < 4; ++mi)
      af2[mi] = *(const short8*)&lds[bo + a_rd + (4 + mi) * 512];
    __builtin_amdgcn_s_setprio(1);
#pragma unroll
    for (int mi = 2; mi < 4; ++mi)
#pragma unroll
      for (int ni = 0; ni < 4; ++ni)
        acc[mi][ni] = __builtin_amdgcn_mfma_f32_16x16x32_bf16(
            af1[mi], bf[ni], acc[mi][ni], 0, 0, 0);
#pragma unroll
    for (int mi = 0; mi < 4; ++mi)
#pragma unroll
      for (int ni = 0; ni < 4; ++ni)
        acc[4 + mi][ni] = __builtin_amdgcn_mfma_f32_16x16x32_bf16(
            af2[mi], bf[ni], acc[4 + mi][ni], 0, 0, 0);
    __builtin_amdgcn_s_setprio(0);
  };

  // Main loop: tiles 0..60 stage tile k+3. The counted vmcnt + raw barrier is
  // the ONLY per-tile sync ("memory" clobber = the tile-boundary fence).
#pragma unroll 1
  for (int k = 0; k < 61; ++k) {
    tile(k, true);
    asm volatile("s_waitcnt vmcnt(8)" ::: "memory");  // tile k+1 resident
    __builtin_amdgcn_s_barrier();
  }
  tile(61, false);
  asm volatile("s_waitcnt vmcnt(4)" ::: "memory");    // tile 62 resident
  __builtin_amdgcn_s_barrier();
  tile(62, false);
  asm volatile("s_waitcnt vmcnt(0)" ::: "memory");    // tile 63 resident
  __builtin_amdgcn_s_barrier();
  tile(63, false);

  // Epilogue: C/D layout col = lane&15, row = quad*4 + reg  [m89-verified]
  float* op = out + (size_t)(m0 + wm * 128 + quad * 4) * N_DIM + n0 + wn * 64 + l15;
#pragma unroll
  for (int mi = 0; mi < 8; ++mi)
#pragma unroll
    for (int r = 0; r < 4; ++r)
#pragma unroll
      for (int ni = 0; ni < 4; ++ni)
        op[(size_t)(mi * 16 + r) * N_DIM + ni * 16] = acc[mi][ni][r];
}

// -----------------------------------------------------------------------------
extern "C" void kernel_launch(void* const* d_in, const int* in_sizes, int n_in,
                              void* d_out, int out_size, void* d_ws, size_t ws_size,
                              hipStream_t stream) {
  const float* x      = (const float*)d_in[0];  // [4,2048,2048] fp32
  const int*   packed = (const int*)d_in[1];    // [5767168] int32 (byte values)
  const float* scales = (const float*)d_in[2];  // [90112]
  const float* zeros  = (const float*)d_in[3];  // [90112]
  const float* lA     = (const float*)d_in[4];  // [2048,16]
  const float* lB     = (const float*)d_in[5];  // [16,5632]
  float* out = (float*)d_out;                   // [4,2048,5632] fp32

  short* xb = (short*)d_ws;                     // x in bf16: 16,777,216 shorts
  short* wb = xb + (size_t)M_DIM * K_DIM;       // W' in bf16: 11,534,336 shorts

  cvt_x_kernel<<<(M_DIM * K_DIM) / (256 * 8), 256, 0, stream>>>(x, xb);
  dequant_lora_kernel<<<N_DIM, 256, 0, stream>>>(packed, scales, zeros, lA, lB, wb);
  gemm_kernel<<<dim3(N_DIM / 256 * (M_DIM / 256)), 512, 0, stream>>>(xb, wb, out);
}

// Round 3
// 456.898 us; speedup vs baseline: 1.1403x; 1.1403x over previous
//
#include <hip/hip_runtime.h>

#define M_DIM 8192
#define K_DIM 2048
#define N_DIM 5632

typedef __attribute__((ext_vector_type(8))) short short8;
typedef __attribute__((ext_vector_type(4))) short s4v;
typedef __attribute__((ext_vector_type(4))) float f32x4;

// fp32 -> bf16 round-to-nearest-even (bit trick; inputs are finite)
__device__ __forceinline__ short f2b(float f) {
  union { float f; unsigned u; } v; v.f = f;
  unsigned r = v.u + 0x7FFFu + ((v.u >> 16) & 1u);
  return (short)(r >> 16);
}

// async global->LDS, 16B per lane. LDS dest must be wave-uniform base + lane*16.
__device__ __forceinline__ void async16(void* lds, const void* g) {
  __builtin_amdgcn_global_load_lds(
      (const __attribute__((address_space(1))) unsigned*)g,
      (__attribute__((address_space(3))) unsigned*)lds,
      16, 0, 0);
}

// ---------------- Kernel 1: x fp32 -> bf16 (fully coalesced) -----------------
__global__ __launch_bounds__(256) void cvt_x_kernel(const float* __restrict__ x,
                                                    short* __restrict__ xb) {
  long t = (long)blockIdx.x * 256 + threadIdx.x;   // 4 elements per thread
  float4 f = ((const float4*)x)[t];                // lane-contiguous 16B
  s4v o;
  o[0] = f2b(f.x); o[1] = f2b(f.y); o[2] = f2b(f.z); o[3] = f2b(f.w);
  *(s4v*)(xb + 4 * t) = o;                         // lane-contiguous 8B
}

// ---------------- Kernel 1b: transpose lA -> lAT[16][2048], fold 2x scale ----
// Read: lane i reads row i (64B contiguous). Write: for fixed r, lanes write
// consecutive floats -> 16 fully-coalesced store streams. 128 KB total, ~2 us.
__global__ __launch_bounds__(256) void lat_kernel(const float* __restrict__ lA,
                                                  float* __restrict__ lAT) {
  int i = blockIdx.x * 256 + threadIdx.x;          // 8 blocks x 256 = 2048
  const float4* row = (const float4*)(lA + (size_t)i * 16);
  float4 v0 = row[0], v1 = row[1], v2 = row[2], v3 = row[3];
  float vals[16] = {v0.x, v0.y, v0.z, v0.w, v1.x, v1.y, v1.z, v1.w,
                    v2.x, v2.y, v2.z, v2.w, v3.x, v3.y, v3.z, v3.w};
#pragma unroll
  for (int r = 0; r < 16; ++r) lAT[r * K_DIM + i] = vals[r] * 2.0f;
}

// ---------------- Kernel 2: dequant int4 + fold rank-16 LoRA into W' ---------
// W'[o][i] = (q - zero[g]) * scale[g] + sum_r lAT[r][i] * lB[r][o]
// lAT is pre-transposed + pre-scaled -> every lora load is lane-contiguous
// (old version read lA rows at 512B lane stride: 64 cachelines/instr, ~740 MB
//  of uncoalesced L1 traffic — the suspected hidden ~150+ us).
__global__ __launch_bounds__(256) void dequant_lora_kernel(
    const int* __restrict__ packed, const float* __restrict__ scales,
    const float* __restrict__ zeros, const float* __restrict__ lAT,
    const float* __restrict__ lB, short* __restrict__ wb) {
  int o = blockIdx.x;
  int i0 = threadIdx.x * 8;                  // 8 consecutive W elements in row o
  long e0 = (long)o * K_DIM + i0;            // flat W index
  int4 p = ((const int4*)packed)[e0 >> 3];   // 4 packed bytes -> 8 codes
  int g = (int)(e0 >> 7);                    // group of 128
  float s = scales[g], z = zeros[g];

  float accv[8];
#pragma unroll
  for (int d = 0; d < 4; ++d) {
    int pv = (&p.x)[d];
    accv[2 * d]     = ((float)(pv & 0xF) - z) * s;
    accv[2 * d + 1] = ((float)((pv >> 4) & 0xF) - z) * s;
  }
#pragma unroll
  for (int r = 0; r < 16; ++r) {
    float b = lB[r * N_DIM + o];             // uniform per block -> scalar load
    const float4* ar = (const float4*)&lAT[r * K_DIM + i0];
    float4 a0 = ar[0], a1 = ar[1];           // lane-contiguous-ish (32B stride)
    accv[0] += a0.x * b; accv[1] += a0.y * b;
    accv[2] += a0.z * b; accv[3] += a0.w * b;
    accv[4] += a1.x * b; accv[5] += a1.y * b;
    accv[6] += a1.z * b; accv[7] += a1.w * b;
  }
  short8 out8;
#pragma unroll
  for (int j = 0; j < 8; ++j) out8[j] = f2b(accv[j]);
  *(short8*)(wb + e0) = out8;
}

// ---------------- Kernel 3: C[m][n] = sum_k X[m][k] * W'[n][k] ---------------
// 256x256 tile, BK=32, 8 waves (2Mx4N), per-wave 128x64 = acc[8][4].
// LDS: 4-deep K-tile ring (128KB), prefetch distance 3, ONE barrier per tile.
// NEW: cross-tile REGISTER prefetch — during tile k, read tile k+1's bf/af1
// into the alternate register set. Phase-1 MFMAs then have ZERO lgkm
// dependency -> the 12 ds_reads drain under MFMA work instead of before it.
// (R2 measured 2670 cyc/tile ~= MFMA 1242 + LDS 1152 serialized; overlapped
//  ideal ~1300.)
// Residency: tile-end wait vmcnt(4) -> at entry to tile k, buffers k AND k+1
// are resident (their stages issued 2-3 tiles = ~5000 cyc ago >> 900 cyc HBM).
// Hazards: all reads of buf (k-1)&3 are lgkm-complete (in regs) before each
// wave passes the end-of-(k-1) barrier; stage into that buf issues after it.
__global__ __launch_bounds__(512, 2) void gemm_kernel(const short* __restrict__ xb,
                                                      const short* __restrict__ wb,
                                                      float* __restrict__ out) {
  // [0,32768): A bufs (4 x 8192 shorts), [32768,65536): B bufs
  __shared__ __align__(16) short lds[65536];   // 128 KB

  const int tid = threadIdx.x;
  const int lane = tid & 63;
  const int wave = tid >> 6;
  const int wm = wave >> 2, wn = wave & 3;     // 2(M) x 4(N) wave grid
  const int l15 = lane & 15, quad = lane >> 4;

  // XCD-aware bijective swizzle: 704 blocks = 8 XCDs x 88
  int flat = blockIdx.x;
  int swz = (flat & 7) * 88 + (flat >> 3);
  int bm = swz / 22, bn = swz - bm * 22;
  const int m0 = bm * 256, n0 = bn * 256;

  const short* a_base = xb + (size_t)m0 * K_DIM;
  const short* b_base = wb + (size_t)n0 * K_DIM;

  // LDS read offsets (shorts). Swizzle: slot s of row r holds chunk s^((r>>1)&3)
  const int rswz = quad ^ ((l15 >> 1) & 3);
  const int a_rd = (wm * 128 + l15) * 32 + rswz * 8;           // + mi*512 + buf
  const int b_rd = 32768 + (wn * 64 + l15) * 32 + rswz * 8;    // + ni*512 + buf

  // Staging: 4 x global_load_lds(16B)/thread/tile; linear LDS dest,
  // inverse-swizzled global source.
  const int srow = tid >> 2;
  const int schunk = (tid & 3) ^ ((srow >> 1) & 3);
  const short* ag0 = a_base + (size_t)srow * K_DIM + schunk * 8;
  const short* ag1 = ag0 + (size_t)128 * K_DIM;
  const short* bg0 = b_base + (size_t)srow * K_DIM + schunk * 8;
  const short* bg1 = bg0 + (size_t)128 * K_DIM;
  const int sl0 = tid * 8, sl1 = (512 + tid) * 8;

  f32x4 acc[8][4] = {};
  short8 bfA[4], af1A[4], bfB[4], af1B[4];   // double-buffered fragment sets

  // Prologue: stage K-tiles 0,1,2 into bufs 0,1,2.
#pragma unroll
  for (int t = 0; t < 3; ++t) {
    const int sb = t * 8192;
    async16(&lds[sb + sl0], ag0 + t * 32);
    async16(&lds[sb + sl1], ag1 + t * 32);
    async16(&lds[32768 + sb + sl0], bg0 + t * 32);
    async16(&lds[32768 + sb + sl1], bg1 + t * 32);
  }
  asm volatile("s_waitcnt vmcnt(4)" ::: "memory");  // tiles 0,1 resident
  __builtin_amdgcn_s_barrier();
  // Preload tile 0's bf/af1 into set A.
#pragma unroll
  for (int ni = 0; ni < 4; ++ni) bfA[ni] = *(const short8*)&lds[b_rd + ni * 512];
#pragma unroll
  for (int mi = 0; mi < 4; ++mi) af1A[mi] = *(const short8*)&lds[a_rd + mi * 512];

  // One tile: af2 reads (current) + next-tile bf/af1 reads + stage issue,
  // then 32 MFMAs whose first half depends only on pre-loaded registers.
  auto tile = [&](int k, short8* bfc, short8* af1c, short8* bfn, short8* af1n,
                  bool do_stage, bool do_pref) {
    const int bo = (k & 3) * 8192;
    const int no_ = ((k + 1) & 3) * 8192;
    const int so = ((k + 3) & 3) * 8192;
    short8 af2[4];
#pragma unroll
    for (int mi = 0; mi < 4; ++mi)
      af2[mi] = *(const short8*)&lds[bo + a_rd + (4 + mi) * 512];
    if (do_pref) {
#pragma unroll
      for (int ni = 0; ni < 4; ++ni)
        bfn[ni] = *(const short8*)&lds[no_ + b_rd + ni * 512];
#pragma unroll
      for (int mi = 0; mi < 4; ++mi)
        af1n[mi] = *(const short8*)&lds[no_ + a_rd + mi * 512];
    }
    if (do_stage) {
      async16(&lds[so + sl0], ag0 + (k + 3) * 32);
      async16(&lds[so + sl1], ag1 + (k + 3) * 32);
      async16(&lds[32768 + so + sl0], bg0 + (k + 3) * 32);
      async16(&lds[32768 + so + sl1], bg1 + (k + 3) * 32);
    }
    __builtin_amdgcn_s_setprio(1);
#pragma unroll
    for (int mi = 0; mi < 4; ++mi)        // phase 1: zero lgkm dependency
#pragma unroll
      for (int ni = 0; ni < 4; ++ni)
        acc[mi][ni] = __builtin_amdgcn_mfma_f32_16x16x32_bf16(
            af1c[mi], bfc[ni], acc[mi][ni], 0, 0, 0);
#pragma unroll
    for (int mi = 0; mi < 4; ++mi)        // phase 2: waits af2 only (lgkmcnt(8))
#pragma unroll
      for (int ni = 0; ni < 4; ++ni)
        acc[4 + mi][ni] = __builtin_amdgcn_mfma_f32_16x16x32_bf16(
            af2[mi], bfc[ni], acc[4 + mi][ni], 0, 0, 0);
    __builtin_amdgcn_s_setprio(0);
  };

  // Steady state: stage k+3, end-of-tile vmcnt(4) keeps k+1,k+2 resident.
#pragma unroll 1
  for (int k = 0; k < 60; k += 2) {
    tile(k, bfA, af1A, bfB, af1B, true, true);
    asm volatile("s_waitcnt vmcnt(4)" ::: "memory");
    __builtin_amdgcn_s_barrier();
    tile(k + 1, bfB, af1B, bfA, af1A, true, true);
    asm volatile("s_waitcnt vmcnt(4)" ::: "memory");
    __builtin_amdgcn_s_barrier();
  }
  tile(60, bfA, af1A, bfB, af1B, true, true);   // stages tile 63 (last stage)
  asm volatile("s_waitcnt vmcnt(4)" ::: "memory");
  __builtin_amdgcn_s_barrier();
  tile(61, bfB, af1B, bfA, af1A, false, true);
  asm volatile("s_waitcnt vmcnt(0)" ::: "memory"); // tile 63 resident
  __builtin_amdgcn_s_barrier();
  tile(62, bfA, af1A, bfB, af1B, false, true);   // no stages pending: no sync
  tile(63, bfB, af1B, bfA, af1A, false, false);

  // Epilogue: C/D layout col = lane&15, row = quad*4 + reg  [m89-verified]
  float* op = out + (size_t)(m0 + wm * 128 + quad * 4) * N_DIM + n0 + wn * 64 + l15;
#pragma unroll
  for (int mi = 0; mi < 8; ++mi)
#pragma unroll
    for (int r = 0; r < 4; ++r)
#pragma unroll
      for (int ni = 0; ni < 4; ++ni)
        op[(size_t)(mi * 16 + r) * N_DIM + ni * 16] = acc[mi][ni][r];
}

// -----------------------------------------------------------------------------
extern "C" void kernel_launch(void* const* d_in, const int* in_sizes, int n_in,
                              void* d_out, int out_size, void* d_ws, size_t ws_size,
                              hipStream_t stream) {
  const float* x      = (const float*)d_in[0];  // [4,2048,2048] fp32
  const int*   packed = (const int*)d_in[1];    // [5767168] int32 (byte values)
  const float* scales = (const float*)d_in[2];  // [90112]
  const float* zeros  = (const float*)d_in[3];  // [90112]
  const float* lA     = (const float*)d_in[4];  // [2048,16]
  const float* lB     = (const float*)d_in[5];  // [16,5632]
  float* out = (float*)d_out;                   // [4,2048,5632] fp32

  short* xb = (short*)d_ws;                     // x in bf16: 16,777,216 shorts
  short* wb = xb + (size_t)M_DIM * K_DIM;       // W' in bf16: 11,534,336 shorts
  // lAT scratch lives in the TAIL of out (32K floats); dequant consumes it
  // before gemm overwrites every element of out.
  float* lAT = out + ((size_t)4 * 2048 * N_DIM - 16 * K_DIM);

  cvt_x_kernel<<<(M_DIM * K_DIM) / (256 * 4), 256, 0, stream>>>(x, xb);
  lat_kernel<<<K_DIM / 256, 256, 0, stream>>>(lA, lAT);
  dequant_lora_kernel<<<N_DIM, 256, 0, stream>>>(packed, scales, zeros, lAT, lB, wb);
  gemm_kernel<<<dim3(N_DIM / 256 * (M_DIM / 256)), 512, 0, stream>>>(xb, wb, out);
}

// Round 4
// 455.648 us; speedup vs baseline: 1.1434x; 1.0027x over previous
//
#include <hip/hip_runtime.h>

#define M_DIM 8192
#define K_DIM 2048
#define N_DIM 5632

typedef __attribute__((ext_vector_type(8))) short short8;
typedef __attribute__((ext_vector_type(4))) short s4v;
typedef __attribute__((ext_vector_type(4))) float f32x4;

// fp32 -> bf16 round-to-nearest-even (bit trick; inputs are finite)
__device__ __forceinline__ short f2b(float f) {
  union { float f; unsigned u; } v; v.f = f;
  unsigned r = v.u + 0x7FFFu + ((v.u >> 16) & 1u);
  return (short)(r >> 16);
}

// async global->LDS, 16B per lane. LDS dest must be wave-uniform base + lane*16.
__device__ __forceinline__ void async16(void* lds, const void* g) {
  __builtin_amdgcn_global_load_lds(
      (const __attribute__((address_space(1))) unsigned*)g,
      (__attribute__((address_space(3))) unsigned*)lds,
      16, 0, 0);
}

// ---------------- Kernel 1: x fp32 -> bf16 (fully coalesced) -----------------
__global__ __launch_bounds__(256) void cvt_x_kernel(const float* __restrict__ x,
                                                    short* __restrict__ xb) {
  long t = (long)blockIdx.x * 256 + threadIdx.x;   // 4 elements per thread
  float4 f = ((const float4*)x)[t];
  s4v o;
  o[0] = f2b(f.x); o[1] = f2b(f.y); o[2] = f2b(f.z); o[3] = f2b(f.w);
  *(s4v*)(xb + 4 * t) = o;
}

// ---------------- Kernel 1b: transpose lA -> lAT[16][2048], fold 2x scale ----
__global__ __launch_bounds__(256) void lat_kernel(const float* __restrict__ lA,
                                                  float* __restrict__ lAT) {
  int i = blockIdx.x * 256 + threadIdx.x;          // 8 blocks x 256 = 2048
  const float4* row = (const float4*)(lA + (size_t)i * 16);
  float4 v0 = row[0], v1 = row[1], v2 = row[2], v3 = row[3];
  float vals[16] = {v0.x, v0.y, v0.z, v0.w, v1.x, v1.y, v1.z, v1.w,
                    v2.x, v2.y, v2.z, v2.w, v3.x, v3.y, v3.z, v3.w};
#pragma unroll
  for (int r = 0; r < 16; ++r) lAT[r * K_DIM + i] = vals[r] * 2.0f;
}

// ---------------- Kernel 2: dequant int4 + fold rank-16 LoRA into W' ---------
// W'[o][i] = (q - zero[g]) * scale[g] + sum_r lAT[r][i] * lB[r][o]
__global__ __launch_bounds__(256) void dequant_lora_kernel(
    const int* __restrict__ packed, const float* __restrict__ scales,
    const float* __restrict__ zeros, const float* __restrict__ lAT,
    const float* __restrict__ lB, short* __restrict__ wb) {
  int o = blockIdx.x;
  int i0 = threadIdx.x * 8;
  long e0 = (long)o * K_DIM + i0;
  int4 p = ((const int4*)packed)[e0 >> 3];
  int g = (int)(e0 >> 7);
  float s = scales[g], z = zeros[g];

  float accv[8];
#pragma unroll
  for (int d = 0; d < 4; ++d) {
    int pv = (&p.x)[d];
    accv[2 * d]     = ((float)(pv & 0xF) - z) * s;
    accv[2 * d + 1] = ((float)((pv >> 4) & 0xF) - z) * s;
  }
#pragma unroll
  for (int r = 0; r < 16; ++r) {
    float b = lB[r * N_DIM + o];             // uniform per block -> scalar load
    const float4* ar = (const float4*)&lAT[r * K_DIM + i0];
    float4 a0 = ar[0], a1 = ar[1];
    accv[0] += a0.x * b; accv[1] += a0.y * b;
    accv[2] += a0.z * b; accv[3] += a0.w * b;
    accv[4] += a1.x * b; accv[5] += a1.y * b;
    accv[6] += a1.z * b; accv[7] += a1.w * b;
  }
  short8 out8;
#pragma unroll
  for (int j = 0; j < 8; ++j) out8[j] = f2b(accv[j]);
  *(short8*)(wb + e0) = out8;
}

// ---------------- Kernel 3: C[m][n] = sum_k X[m][k] * W'[n][k] ---------------
// 256x256 tile, BK=32, 8 waves (2Mx4N), per-wave 128x64 = acc[8][4].
// 4-deep K-tile ring (128KB), prefetch distance 3, vmcnt(4) tile gate.
// NEW (R4): 4 phases per tile, 8 MFMA each. Phase p issues <=4 ds_reads FOR
// PHASE p+1 + 1 stage load, then MFMAs on registers read LAST phase, then
// barrier. Per-phase LDS drain (16-32 reads/CU = 192-384 cyc) fits under the
// per-phase MFMA cluster (~300 cyc) -> pipes overlap instead of serializing.
// (R1-R3 all measured ~2600-2860 cyc/tile = MFMA 1150 + LDS-drain 1150
//  serialized: the 96-read post-barrier burst completes near the end of its
//  drain for EVERY wave, stalling all of them regardless of prefetch.)
// Hazards:
//   - stage into slot (k+3)&3 issues after the ph3 barrier of tile k-1; every
//     wave's reads of that slot were CONSUMED by its ph3 MFMA before that
//     barrier -> no read-vs-DMA-write race.
//   - next-tile reads (bn in ph1/ph2, af01 in ph3) gated by tile-(k-1)-end
//     vmcnt(4): tile k+1 resident (4-deep ring, distance 3).
__global__ __launch_bounds__(512, 2) void gemm_kernel(const short* __restrict__ xb,
                                                      const short* __restrict__ wb,
                                                      float* __restrict__ out) {
  // [0,32768): A bufs (4 x 8192 shorts), [32768,65536): B bufs
  __shared__ __align__(16) short lds[65536];   // 128 KB

  const int tid = threadIdx.x;
  const int lane = tid & 63;
  const int wave = tid >> 6;
  const int wm = wave >> 2, wn = wave & 3;     // 2(M) x 4(N) wave grid
  const int l15 = lane & 15, quad = lane >> 4;

  // XCD-aware bijective swizzle: 704 blocks = 8 XCDs x 88
  int flat = blockIdx.x;
  int swz = (flat & 7) * 88 + (flat >> 3);
  int bm = swz / 22, bn_ = swz - bm * 22;
  const int m0 = bm * 256, n0 = bn_ * 256;

  const short* a_base = xb + (size_t)m0 * K_DIM;
  const short* b_base = wb + (size_t)n0 * K_DIM;

  // LDS read offsets. Swizzle: slot s of row r holds chunk s ^ ((r>>1)&3).
  const int rswz = quad ^ ((l15 >> 1) & 3);
  const int a_rd = (wm * 128 + l15) * 32 + rswz * 8;           // + mi*512 + buf
  const int b_rd = 32768 + (wn * 64 + l15) * 32 + rswz * 8;    // + ni*512 + buf

  // Staging: 4 x global_load_lds(16B)/thread/tile; linear LDS dest,
  // inverse-swizzled global source.
  const int srow = tid >> 2;
  const int schunk = (tid & 3) ^ ((srow >> 1) & 3);
  const short* ag0 = a_base + (size_t)srow * K_DIM + schunk * 8;
  const short* ag1 = ag0 + (size_t)128 * K_DIM;
  const short* bg0 = b_base + (size_t)srow * K_DIM + schunk * 8;
  const short* bg1 = bg0 + (size_t)128 * K_DIM;
  const int sl0 = tid * 8, sl1 = (512 + tid) * 8;

  f32x4 acc[8][4] = {};
  short8 bfA[4], bfB[4], aX[2], aY[2];   // B frags dbuf; A frag pair dbuf

  // Prologue: stage K-tiles 0,1,2 into ring slots 0,1,2.
#pragma unroll
  for (int t = 0; t < 3; ++t) {
    const int sb = t * 8192;
    async16(&lds[sb + sl0], ag0 + t * 32);
    async16(&lds[sb + sl1], ag1 + t * 32);
    async16(&lds[32768 + sb + sl0], bg0 + t * 32);
    async16(&lds[32768 + sb + sl1], bg1 + t * 32);
  }
  asm volatile("s_waitcnt vmcnt(4)" ::: "memory");  // tiles 0,1 resident
  __builtin_amdgcn_s_barrier();
  // Prime: tile 0's B frags and A frag-pair 0 (one-time lgkm stall, ~200cy).
#pragma unroll
  for (int ni = 0; ni < 4; ++ni) bfA[ni] = *(const short8*)&lds[b_rd + ni * 512];
  aX[0] = *(const short8*)&lds[a_rd];
  aX[1] = *(const short8*)&lds[a_rd + 512];

  // One tile = 4 phases. bc = current tile's B frags, bn = next tile's.
  // aX enters holding af01(tile k), exits holding af01(tile k+1).
  auto tile = [&](int k, short8* bc, short8* bnx, bool do_stage, bool do_next,
                  int vm) {
    const int bo = (k & 3) * 8192;
    const int no_ = ((k + 1) & 3) * 8192;
    const int so = ((k + 3) & 3) * 8192;
    // ---- phase 0: read af23->aY; stage A-half0; MFMA mi 0,1 (aX) ----
    aY[0] = *(const short8*)&lds[bo + a_rd + 2 * 512];
    aY[1] = *(const short8*)&lds[bo + a_rd + 3 * 512];
    if (do_stage) async16(&lds[so + sl0], ag0 + (k + 3) * 32);
    __builtin_amdgcn_s_setprio(1);
#pragma unroll
    for (int ni = 0; ni < 4; ++ni) {
      acc[0][ni] = __builtin_amdgcn_mfma_f32_16x16x32_bf16(aX[0], bc[ni], acc[0][ni], 0, 0, 0);
      acc[1][ni] = __builtin_amdgcn_mfma_f32_16x16x32_bf16(aX[1], bc[ni], acc[1][ni], 0, 0, 0);
    }
    __builtin_amdgcn_s_setprio(0);
    __builtin_amdgcn_s_barrier();
    // ---- phase 1: read af45->aX, bn01; stage A-half1; MFMA mi 2,3 (aY) ----
    aX[0] = *(const short8*)&lds[bo + a_rd + 4 * 512];
    aX[1] = *(const short8*)&lds[bo + a_rd + 5 * 512];
    if (do_next) {
      bnx[0] = *(const short8*)&lds[no_ + b_rd];
      bnx[1] = *(const short8*)&lds[no_ + b_rd + 512];
    }
    if (do_stage) async16(&lds[so + sl1], ag1 + (k + 3) * 32);
    __builtin_amdgcn_s_setprio(1);
#pragma unroll
    for (int ni = 0; ni < 4; ++ni) {
      acc[2][ni] = __builtin_amdgcn_mfma_f32_16x16x32_bf16(aY[0], bc[ni], acc[2][ni], 0, 0, 0);
      acc[3][ni] = __builtin_amdgcn_mfma_f32_16x16x32_bf16(aY[1], bc[ni], acc[3][ni], 0, 0, 0);
    }
    __builtin_amdgcn_s_setprio(0);
    __builtin_amdgcn_s_barrier();
    // ---- phase 2: read af67->aY, bn23; stage B-half0; MFMA mi 4,5 (aX) ----
    aY[0] = *(const short8*)&lds[bo + a_rd + 6 * 512];
    aY[1] = *(const short8*)&lds[bo + a_rd + 7 * 512];
    if (do_next) {
      bnx[2] = *(const short8*)&lds[no_ + b_rd + 2 * 512];
      bnx[3] = *(const short8*)&lds[no_ + b_rd + 3 * 512];
    }
    if (do_stage) async16(&lds[32768 + so + sl0], bg0 + (k + 3) * 32);
    __builtin_amdgcn_s_setprio(1);
#pragma unroll
    for (int ni = 0; ni < 4; ++ni) {
      acc[4][ni] = __builtin_amdgcn_mfma_f32_16x16x32_bf16(aX[0], bc[ni], acc[4][ni], 0, 0, 0);
      acc[5][ni] = __builtin_amdgcn_mfma_f32_16x16x32_bf16(aX[1], bc[ni], acc[5][ni], 0, 0, 0);
    }
    __builtin_amdgcn_s_setprio(0);
    __builtin_amdgcn_s_barrier();
    // ---- phase 3: read next af01->aX; stage B-half1; MFMA mi 6,7 (aY);
    //      vmcnt gate (tile k+2 residency for tile k+1's next-reads) ----
    if (do_next) {
      aX[0] = *(const short8*)&lds[no_ + a_rd];
      aX[1] = *(const short8*)&lds[no_ + a_rd + 512];
    }
    if (do_stage) async16(&lds[32768 + so + sl1], bg1 + (k + 3) * 32);
    __builtin_amdgcn_s_setprio(1);
#pragma unroll
    for (int ni = 0; ni < 4; ++ni) {
      acc[6][ni] = __builtin_amdgcn_mfma_f32_16x16x32_bf16(aY[0], bc[ni], acc[6][ni], 0, 0, 0);
      acc[7][ni] = __builtin_amdgcn_mfma_f32_16x16x32_bf16(aY[1], bc[ni], acc[7][ni], 0, 0, 0);
    }
    __builtin_amdgcn_s_setprio(0);
    if (vm == 4) asm volatile("s_waitcnt vmcnt(4)" ::: "memory");
    else if (vm == 0) asm volatile("s_waitcnt vmcnt(0)" ::: "memory");
    __builtin_amdgcn_s_barrier();
  };

#pragma unroll 1
  for (int k = 0; k < 60; k += 2) {
    tile(k,     bfA, bfB, true, true, 4);
    tile(k + 1, bfB, bfA, true, true, 4);
  }
  tile(60, bfA, bfB, true,  true, 4);
  tile(61, bfB, bfA, false, true, 0);   // drain: tile 63 resident
  tile(62, bfA, bfB, false, true, -1);
  tile(63, bfB, bfA, false, false, -1);

  // Epilogue: C/D layout col = lane&15, row = quad*4 + reg  [m89-verified]
  // Non-temporal: out is written once, never re-read -> keep it out of L2/L3
  // so xb/wb stay resident (attacks the 5.5x HBM over-fetch).
  float* op = out + (size_t)(m0 + wm * 128 + quad * 4) * N_DIM + n0 + wn * 64 + l15;
#pragma unroll
  for (int mi = 0; mi < 8; ++mi)
#pragma unroll
    for (int r = 0; r < 4; ++r)
#pragma unroll
      for (int ni = 0; ni < 4; ++ni)
        __builtin_nontemporal_store(acc[mi][ni][r],
                                    &op[(size_t)(mi * 16 + r) * N_DIM + ni * 16]);
}

// -----------------------------------------------------------------------------
extern "C" void kernel_launch(void* const* d_in, const int* in_sizes, int n_in,
                              void* d_out, int out_size, void* d_ws, size_t ws_size,
                              hipStream_t stream) {
  const float* x      = (const float*)d_in[0];  // [4,2048,2048] fp32
  const int*   packed = (const int*)d_in[1];    // [5767168] int32 (byte values)
  const float* scales = (const float*)d_in[2];  // [90112]
  const float* zeros  = (const float*)d_in[3];  // [90112]
  const float* lA     = (const float*)d_in[4];  // [2048,16]
  const float* lB     = (const float*)d_in[5];  // [16,5632]
  float* out = (float*)d_out;                   // [4,2048,5632] fp32

  short* xb = (short*)d_ws;                     // x in bf16: 16,777,216 shorts
  short* wb = xb + (size_t)M_DIM * K_DIM;       // W' in bf16: 11,534,336 shorts
  // lAT scratch lives in the TAIL of out; dequant consumes it before gemm
  // overwrites every element of out.
  float* lAT = out + ((size_t)4 * 2048 * N_DIM - 16 * K_DIM);

  cvt_x_kernel<<<(M_DIM * K_DIM) / (256 * 4), 256, 0, stream>>>(x, xb);
  lat_kernel<<<K_DIM / 256, 256, 0, stream>>>(lA, lAT);
  dequant_lora_kernel<<<N_DIM, 256, 0, stream>>>(packed, scales, zeros, lAT, lB, wb);
  gemm_kernel<<<dim3(N_DIM / 256 * (M_DIM / 256)), 512, 0, stream>>>(xb, wb, out);
}